// Round 4
// baseline (619.493 us; speedup 1.0000x reference)
//
#include <hip/hip_runtime.h>
#include <hip/hip_bf16.h>

constexpr int D = 128;
constexpr int NB_SCAN = 512;  // max scan blocks per layer (ceil(100000/256)=391)

using bf16x8 = __attribute__((ext_vector_type(8))) short;
using f32x4 = __attribute__((ext_vector_type(4))) float;

__device__ inline ushort f2bf(float f) {
  union { float f; uint u; } v; v.f = f;
  uint r = v.u + 0x7fff + ((v.u >> 16) & 1);
  return (ushort)(r >> 16);
}
__device__ inline float bflo(uint p) {
  union { uint u; float f; } v; v.u = p << 16; return v.f;
}
__device__ inline float bfhi(uint p) {
  union { uint u; float f; } v; v.u = p & 0xffff0000u; return v.f;
}

__global__ void fill_int_zero(int* __restrict__ p, int n) {
  int i = blockIdx.x * blockDim.x + threadIdx.x;
  if (i < n) p[i] = 0;
}

__global__ void cvt_f32_bf16(const float4* __restrict__ x, uint2* __restrict__ o, long n4) {
  long i = (long)blockIdx.x * blockDim.x + threadIdx.x;
  long stride = (long)gridDim.x * blockDim.x;
  for (; i < n4; i += stride) {
    float4 v = x[i];
    uint2 r;
    r.x = (uint)f2bf(v.x) | ((uint)f2bf(v.y) << 16);
    r.y = (uint)f2bf(v.z) | ((uint)f2bf(v.w) << 16);
    o[i] = r;
  }
}

// Combined weight, bf16, row-major [OC][256]: k<128 -> Wl[c][k], else Wr[c][k-128]
__global__ void prep_w(const float* __restrict__ Wl, const float* __restrict__ Wr,
                       ushort* __restrict__ Wc, int OC) {
  int t = blockIdx.x * blockDim.x + threadIdx.x;
  if (t < OC * 256) {
    int c = t >> 8, k = t & 255;
    float v = (k < 128) ? Wl[c * 128 + k] : Wr[c * 128 + (k - 128)];
    Wc[t] = f2bf(v);
  }
}

// ---- batched (3-layer) CSR build: blockIdx.y = layer ----
__global__ void count_dst_all(const int* __restrict__ ei, int* __restrict__ cnt, int N, int E) {
  int l = blockIdx.y;
  const int* dst = ei + (size_t)(2 * l + 1) * E;
  int e = blockIdx.x * 256 + threadIdx.x;
  if (e < E) atomicAdd(&cnt[l * N + dst[e]], 1);
}

__global__ void scan_block_all(const int* __restrict__ cnt, int* __restrict__ row_excl,
                               int* __restrict__ bsums, int N) {
  int l = blockIdx.y;
  __shared__ int sm[256];
  int i = blockIdx.x * 256 + threadIdx.x;
  int v = (i < N) ? cnt[l * N + i] : 0;
  sm[threadIdx.x] = v;
  __syncthreads();
  for (int off = 1; off < 256; off <<= 1) {
    int t = (threadIdx.x >= off) ? sm[threadIdx.x - off] : 0;
    __syncthreads();
    sm[threadIdx.x] += t;
    __syncthreads();
  }
  if (i < N) row_excl[l * N + i] = sm[threadIdx.x] - v;
  if (threadIdx.x == 255) bsums[l * NB_SCAN + blockIdx.x] = sm[255];
}

__global__ void scan_sums_all(int* __restrict__ bsums, int nb) {
  int l = blockIdx.y;
  __shared__ int sm[NB_SCAN];
  int v = (threadIdx.x < nb) ? bsums[l * NB_SCAN + threadIdx.x] : 0;
  sm[threadIdx.x] = v;
  __syncthreads();
  for (int off = 1; off < NB_SCAN; off <<= 1) {
    int t = (threadIdx.x >= off) ? sm[threadIdx.x - off] : 0;
    __syncthreads();
    sm[threadIdx.x] += t;
    __syncthreads();
  }
  if (threadIdx.x < nb) bsums[l * NB_SCAN + threadIdx.x] = sm[threadIdx.x] - v;
}

__global__ void scan_fin_all(int* __restrict__ row_start, const int* __restrict__ bsums,
                             int* __restrict__ cursor, int N) {
  int l = blockIdx.y;
  int i = blockIdx.x * 256 + threadIdx.x;
  if (i < N) {
    int v = row_start[l * N + i] + bsums[l * NB_SCAN + blockIdx.x];
    row_start[l * N + i] = v;
    cursor[l * N + i] = v;
  }
}

__global__ void fill_edges_all(const int* __restrict__ ei, int* __restrict__ cursor,
                               int* __restrict__ esrc, int N, int E) {
  int l = blockIdx.y;
  const int* src = ei + (size_t)(2 * l) * E;
  const int* dst = src + E;
  int e = blockIdx.x * 256 + threadIdx.x;
  if (e < E) {
    int pos = atomicAdd(&cursor[l * N + dst[e]], 1);
    esrc[(size_t)l * E + pos] = src[e];
  }
}

// ---- fused layer: aggregate (gather-mean into swizzled LDS) + MFMA linear ----
// Block: 64 nodes, 4 waves. Phase 1: wave w aggregates nodes [w*16, +16) into LDS.
// Phase 2: C[64 x OC] = [mean | h] @ Wc^T + bl (wave w owns cols [w*OC/4, +OC/4)).
// LDS row layout: 64 uints/row, 16B-group XOR swizzle grp' = grp ^ (nl & 7).
template <int OC, bool RELU, bool F32OUT>
__global__ void sage_layer(const ushort* __restrict__ hb, const int* __restrict__ esrc,
                           const int* __restrict__ row_start, const int* __restrict__ cnt,
                           const ushort* __restrict__ Wc, const float* __restrict__ bl,
                           void* __restrict__ outv, int N) {
  constexpr int CT = OC / 64;  // 16-col tiles per wave
  __shared__ uint smean[64 * 64];
  int tid = threadIdx.x;
  int w = tid >> 6, lane = tid & 63;
  int g = lane >> 4, r16 = lane & 15;
  int r0 = blockIdx.x * 64;
  const uint* hp = (const uint*)hb;  // feature rows: 64 uints (128 bf16)

  // Phase 1: aggregation. Each lane owns one uint (2 channels) of the row.
  for (int i = 0; i < 16; ++i) {
    int nl = w * 16 + i;
    int node = r0 + nl;
    float ax0 = 0.f, ay0 = 0.f, ax1 = 0.f, ay1 = 0.f;
    float ax2 = 0.f, ay2 = 0.f, ax3 = 0.f, ay3 = 0.f;
    int deg = 0;
    if (node < N) {
      deg = cnt[node];
      int start = row_start[node];
      for (int j = 0; j < deg; j += 4) {
        int n0 = (j + 0 < deg) ? esrc[start + j + 0] : -1;
        int n1 = (j + 1 < deg) ? esrc[start + j + 1] : -1;
        int n2 = (j + 2 < deg) ? esrc[start + j + 2] : -1;
        int n3 = (j + 3 < deg) ? esrc[start + j + 3] : -1;
        if (n0 >= 0) { uint v = hp[(size_t)n0 * 64 + lane]; ax0 += bflo(v); ay0 += bfhi(v); }
        if (n1 >= 0) { uint v = hp[(size_t)n1 * 64 + lane]; ax1 += bflo(v); ay1 += bfhi(v); }
        if (n2 >= 0) { uint v = hp[(size_t)n2 * 64 + lane]; ax2 += bflo(v); ay2 += bfhi(v); }
        if (n3 >= 0) { uint v = hp[(size_t)n3 * 64 + lane]; ax3 += bflo(v); ay3 += bfhi(v); }
      }
    }
    float inv = 1.0f / fmaxf((float)deg, 1.0f);
    float sx = ((ax0 + ax1) + (ax2 + ax3)) * inv;
    float sy = ((ay0 + ay1) + (ay2 + ay3)) * inv;
    uint packed = (uint)f2bf(sx) | ((uint)f2bf(sy) << 16);
    smean[nl * 64 + (((lane >> 2) ^ (nl & 7)) << 2) + (lane & 3)] = packed;
  }
  __syncthreads();

  // Phase 2: MFMA. B-frags from Wc (row-major => contiguous 16B), bias per col.
  int c0 = w * (OC / 4);
  bf16x8 b[CT][8];
  float bias[CT];
#pragma unroll
  for (int ct = 0; ct < CT; ++ct) {
    int col = c0 + ct * 16 + r16;
    const ushort* wrow = Wc + (size_t)col * 256 + g * 8;
#pragma unroll
    for (int ks = 0; ks < 8; ++ks)
      b[ct][ks] = *reinterpret_cast<const bf16x8*>(wrow + ks * 32);
    bias[ct] = bl[col];
  }

  f32x4 acc[4][CT];
#pragma unroll
  for (int rt = 0; rt < 4; ++rt)
#pragma unroll
    for (int ct = 0; ct < CT; ++ct)
      acc[rt][ct] = (f32x4){0.f, 0.f, 0.f, 0.f};

#pragma unroll
  for (int rt = 0; rt < 4; ++rt) {
    int nl = rt * 16 + r16;
    int rowg = min(r0 + nl, N - 1);
    const ushort* ah = hb + (size_t)rowg * 128 + g * 8;
#pragma unroll
    for (int ks = 0; ks < 4; ++ks) {
      // mean A-frag from LDS, swizzled: 16B group (ks*4+g) ^ (nl&7)
      const bf16x8 am =
          *reinterpret_cast<const bf16x8*>(&smean[nl * 64 + ((((ks << 2) + g) ^ (nl & 7)) << 2)]);
#pragma unroll
      for (int ct = 0; ct < CT; ++ct)
        acc[rt][ct] = __builtin_amdgcn_mfma_f32_16x16x32_bf16(am, b[ct][ks], acc[rt][ct], 0, 0, 0);
    }
#pragma unroll
    for (int ks = 0; ks < 4; ++ks) {
      bf16x8 a = *reinterpret_cast<const bf16x8*>(ah + ks * 32);
#pragma unroll
      for (int ct = 0; ct < CT; ++ct)
        acc[rt][ct] =
            __builtin_amdgcn_mfma_f32_16x16x32_bf16(a, b[ct][ks + 4], acc[rt][ct], 0, 0, 0);
    }
  }

  // Epilogue. C/D layout: col = lane&15, row = (lane>>4)*4 + reg  [m89-verified]
#pragma unroll
  for (int rt = 0; rt < 4; ++rt) {
#pragma unroll
    for (int ct = 0; ct < CT; ++ct) {
      int col = c0 + ct * 16 + r16;
#pragma unroll
      for (int reg = 0; reg < 4; ++reg) {
        int row = r0 + rt * 16 + g * 4 + reg;
        if (row < N) {
          float v = acc[rt][ct][reg] + bias[ct];
          if (RELU) v = fmaxf(v, 0.0f);
          if (F32OUT)
            ((float*)outv)[(size_t)row * OC + col] = v;
          else
            ((ushort*)outv)[(size_t)row * OC + col] = f2bf(v);
        }
      }
    }
  }
}

extern "C" void kernel_launch(void* const* d_in, const int* in_sizes, int n_in,
                              void* d_out, int out_size, void* d_ws, size_t ws_size,
                              hipStream_t stream) {
  const float* x = (const float*)d_in[0];
  const int* ei = (const int*)d_in[1];
  const float* Wl0 = (const float*)d_in[2];
  const float* bl0 = (const float*)d_in[3];
  const float* Wr0 = (const float*)d_in[4];
  const float* Wl1 = (const float*)d_in[5];
  const float* bl1 = (const float*)d_in[6];
  const float* Wr1 = (const float*)d_in[7];
  const float* Wl2 = (const float*)d_in[8];
  const float* bl2 = (const float*)d_in[9];
  const float* Wr2 = (const float*)d_in[10];
  float* out = (float*)d_out;

  const int N = in_sizes[0] / D;  // 100000
  const int E = in_sizes[1] / 6;  // 625000

  char* ws = (char*)d_ws;
  size_t featB = (size_t)N * D * sizeof(ushort);  // 25.6 MB
  ushort* hb0 = (ushort*)ws;
  ushort* hb1 = (ushort*)(ws + featB);
  ushort* Wc0 = (ushort*)(ws + 2 * featB);
  ushort* Wc1 = Wc0 + 128 * 256;
  ushort* Wc2 = Wc1 + 128 * 256;
  int* cnt = (int*)(Wc2 + 64 * 256);      // [3N]
  int* row_start = cnt + 3 * N;           // [3N]
  int* cursor = row_start + 3 * N;        // [3N]
  int* bsums = cursor + 3 * N;            // [3*NB_SCAN]
  int* esrc = bsums + 3 * NB_SCAN;        // [3E]

  const int nbN = (N + 255) / 256;
  const int nbE = (E + 255) / 256;
  const int linGrid = (N + 63) / 64;

  cvt_f32_bf16<<<2048, 256, 0, stream>>>((const float4*)x, (uint2*)hb0, (long)N * D / 4);
  prep_w<<<(128 * 256 + 255) / 256, 256, 0, stream>>>(Wl0, Wr0, Wc0, 128);
  prep_w<<<(128 * 256 + 255) / 256, 256, 0, stream>>>(Wl1, Wr1, Wc1, 128);
  prep_w<<<(64 * 256 + 255) / 256, 256, 0, stream>>>(Wl2, Wr2, Wc2, 64);

  // CSR build for all 3 layers, batched
  fill_int_zero<<<(3 * N + 255) / 256, 256, 0, stream>>>(cnt, 3 * N);
  count_dst_all<<<dim3(nbE, 3), 256, 0, stream>>>(ei, cnt, N, E);
  scan_block_all<<<dim3(nbN, 3), 256, 0, stream>>>(cnt, row_start, bsums, N);
  scan_sums_all<<<dim3(1, 3), NB_SCAN, 0, stream>>>(bsums, nbN);
  scan_fin_all<<<dim3(nbN, 3), 256, 0, stream>>>(row_start, bsums, cursor, N);
  fill_edges_all<<<dim3(nbE, 3), 256, 0, stream>>>(ei, cursor, esrc, N, E);

  sage_layer<128, true, false><<<linGrid, 256, 0, stream>>>(
      hb0, esrc, row_start, cnt, Wc0, bl0, hb1, N);
  sage_layer<128, true, false><<<linGrid, 256, 0, stream>>>(
      hb1, esrc + (size_t)E, row_start + N, cnt + N, Wc1, bl1, hb0, N);
  sage_layer<64, false, true><<<linGrid, 256, 0, stream>>>(
      hb0, esrc + (size_t)2 * E, row_start + 2 * N, cnt + 2 * N, Wc2, bl2, out, N);
}

// Round 5
// 573.431 us; speedup vs baseline: 1.0803x; 1.0803x over previous
//
#include <hip/hip_runtime.h>
#include <hip/hip_bf16.h>

constexpr int D = 128;
constexpr int NB_SCAN = 512;  // max scan blocks per layer (ceil(100000/256)=391)

using bf16x8 = __attribute__((ext_vector_type(8))) short;
using f32x4 = __attribute__((ext_vector_type(4))) float;

__device__ inline ushort f2bf(float f) {
  union { float f; uint u; } v; v.f = f;
  uint r = v.u + 0x7fff + ((v.u >> 16) & 1);
  return (ushort)(r >> 16);
}
__device__ inline float bflo(uint p) {
  union { uint u; float f; } v; v.u = p << 16; return v.f;
}
__device__ inline float bfhi(uint p) {
  union { uint u; float f; } v; v.u = p & 0xffff0000u; return v.f;
}

__global__ void fill_int_zero(int* __restrict__ p, int n) {
  int i = blockIdx.x * blockDim.x + threadIdx.x;
  if (i < n) p[i] = 0;
}

__global__ void cvt_f32_bf16(const float4* __restrict__ x, uint2* __restrict__ o, long n4) {
  long i = (long)blockIdx.x * blockDim.x + threadIdx.x;
  long stride = (long)gridDim.x * blockDim.x;
  for (; i < n4; i += stride) {
    float4 v = x[i];
    uint2 r;
    r.x = (uint)f2bf(v.x) | ((uint)f2bf(v.y) << 16);
    r.y = (uint)f2bf(v.z) | ((uint)f2bf(v.w) << 16);
    o[i] = r;
  }
}

// Combined weight, bf16, row-major [OC][256]: k<128 -> Wl[c][k], else Wr[c][k-128]
__global__ void prep_w(const float* __restrict__ Wl, const float* __restrict__ Wr,
                       ushort* __restrict__ Wc, int OC) {
  int t = blockIdx.x * blockDim.x + threadIdx.x;
  if (t < OC * 256) {
    int c = t >> 8, k = t & 255;
    float v = (k < 128) ? Wl[c * 128 + k] : Wr[c * 128 + (k - 128)];
    Wc[t] = f2bf(v);
  }
}

// ---- batched (3-layer) CSR build: blockIdx.y = layer ----
__global__ void count_dst_all(const int* __restrict__ ei, int* __restrict__ cnt, int N, int E) {
  int l = blockIdx.y;
  const int* dst = ei + (size_t)(2 * l + 1) * E;
  int e = blockIdx.x * 256 + threadIdx.x;
  if (e < E) atomicAdd(&cnt[l * N + dst[e]], 1);
}

__global__ void scan_block_all(const int* __restrict__ cnt, int* __restrict__ row_excl,
                               int* __restrict__ bsums, int N) {
  int l = blockIdx.y;
  __shared__ int sm[256];
  int i = blockIdx.x * 256 + threadIdx.x;
  int v = (i < N) ? cnt[l * N + i] : 0;
  sm[threadIdx.x] = v;
  __syncthreads();
  for (int off = 1; off < 256; off <<= 1) {
    int t = (threadIdx.x >= off) ? sm[threadIdx.x - off] : 0;
    __syncthreads();
    sm[threadIdx.x] += t;
    __syncthreads();
  }
  if (i < N) row_excl[l * N + i] = sm[threadIdx.x] - v;
  if (threadIdx.x == 255) bsums[l * NB_SCAN + blockIdx.x] = sm[255];
}

__global__ void scan_sums_all(int* __restrict__ bsums, int nb) {
  int l = blockIdx.y;
  __shared__ int sm[NB_SCAN];
  int v = (threadIdx.x < nb) ? bsums[l * NB_SCAN + threadIdx.x] : 0;
  sm[threadIdx.x] = v;
  __syncthreads();
  for (int off = 1; off < NB_SCAN; off <<= 1) {
    int t = (threadIdx.x >= off) ? sm[threadIdx.x - off] : 0;
    __syncthreads();
    sm[threadIdx.x] += t;
    __syncthreads();
  }
  if (threadIdx.x < nb) bsums[l * NB_SCAN + threadIdx.x] = sm[threadIdx.x] - v;
}

__global__ void scan_fin_all(int* __restrict__ row_start, const int* __restrict__ bsums,
                             int* __restrict__ cursor, int N) {
  int l = blockIdx.y;
  int i = blockIdx.x * 256 + threadIdx.x;
  if (i < N) {
    int v = row_start[l * N + i] + bsums[l * NB_SCAN + blockIdx.x];
    row_start[l * N + i] = v;
    cursor[l * N + i] = v;
  }
}

// esrc write via atomicExch: atomics execute at the memory-side coherent point (LLC),
// avoiding partial-line write-through to HBM that plain scattered stores incur
// (round-4 counters: plain store version had WRITE_SIZE 122 MB for ~9 MB useful).
__global__ void fill_edges_all(const int* __restrict__ ei, int* __restrict__ cursor,
                               int* __restrict__ esrc, int N, int E) {
  int l = blockIdx.y;
  const int* src = ei + (size_t)(2 * l) * E;
  const int* dst = src + E;
  int e = blockIdx.x * 256 + threadIdx.x;
  if (e < E) {
    int pos = atomicAdd(&cursor[l * N + dst[e]], 1);
    atomicExch(&esrc[(size_t)l * E + pos], src[e]);
  }
}

// One 64-lane wave per node: gather-sum bf16 neighbor rows (fp32 acc), write bf16 mean.
// 8-wide predicated unroll: avg degree is 6.25, so typically ONE latency round
// (8 index s_loads -> 8 gathers in flight) instead of a 2-4 deep dependent chain.
__global__ void aggregate_mean(const ushort* __restrict__ h, const int* __restrict__ esrc,
                               const int* __restrict__ row_start, const int* __restrict__ cnt,
                               ushort* __restrict__ mean, int N) {
  int node = blockIdx.x * (blockDim.x >> 6) + (threadIdx.x >> 6);
  if (node >= N) return;
  int lane = threadIdx.x & 63;
  int start = row_start[node];
  int deg = cnt[node];
  const uint* hp = (const uint*)h;  // row stride 64 uints
  float ax[8], ay[8];
#pragma unroll
  for (int u = 0; u < 8; ++u) { ax[u] = 0.f; ay[u] = 0.f; }
  for (int j = 0; j < deg; j += 8) {
    int idx[8];
#pragma unroll
    for (int u = 0; u < 8; ++u) idx[u] = (j + u < deg) ? esrc[start + j + u] : -1;
#pragma unroll
    for (int u = 0; u < 8; ++u) {
      if (idx[u] >= 0) {
        uint v = hp[(size_t)idx[u] * 64 + lane];
        ax[u] += bflo(v);
        ay[u] += bfhi(v);
      }
    }
  }
  float sx = ((ax[0] + ax[1]) + (ax[2] + ax[3])) + ((ax[4] + ax[5]) + (ax[6] + ax[7]));
  float sy = ((ay[0] + ay[1]) + (ay[2] + ay[3])) + ((ay[4] + ay[5]) + (ay[6] + ay[7]));
  float inv = 1.0f / fmaxf((float)deg, 1.0f);
  uint r = (uint)f2bf(sx * inv) | ((uint)f2bf(sy * inv) << 16);
  ((uint*)mean)[(size_t)node * 64 + lane] = r;
}

// MFMA linear: C[N x OC] = [mean|h] (N x 256, bf16) @ Wc^T + bl, optional relu.
// Block: 64 rows x OC cols, 4 waves; wave w owns cols [w*OC/4, +OC/4) (CT 16-col tiles),
// B-frags held in registers (Wc row-major => contiguous 16B frag loads).
template <int OC, bool RELU, bool F32OUT>
__global__ void sage_linear_mfma(const ushort* __restrict__ mb, const ushort* __restrict__ hb,
                                 const ushort* __restrict__ Wc, const float* __restrict__ bl,
                                 void* __restrict__ outv, int N) {
  constexpr int CT = OC / 64;  // col-tiles per wave: 128 -> 2, 64 -> 1
  int tid = threadIdx.x;
  int w = tid >> 6, lane = tid & 63;
  int g = lane >> 4, r16 = lane & 15;
  int r0 = blockIdx.x * 64;
  int c0 = w * (OC / 4);

  bf16x8 b[CT][8];
  float bias[CT];
#pragma unroll
  for (int ct = 0; ct < CT; ++ct) {
    int col = c0 + ct * 16 + r16;
    const ushort* wrow = Wc + (size_t)col * 256 + g * 8;
#pragma unroll
    for (int ks = 0; ks < 8; ++ks)
      b[ct][ks] = *reinterpret_cast<const bf16x8*>(wrow + ks * 32);
    bias[ct] = bl[col];
  }

  f32x4 acc[4][CT];
#pragma unroll
  for (int rt = 0; rt < 4; ++rt)
#pragma unroll
    for (int ct = 0; ct < CT; ++ct)
      acc[rt][ct] = (f32x4){0.f, 0.f, 0.f, 0.f};

#pragma unroll
  for (int rt = 0; rt < 4; ++rt) {
    int row = r0 + rt * 16 + r16;
    row = min(row, N - 1);
    const ushort* am = mb + (size_t)row * 128 + g * 8;
    const ushort* ah = hb + (size_t)row * 128 + g * 8;
#pragma unroll
    for (int ks = 0; ks < 4; ++ks) {
      bf16x8 a = *reinterpret_cast<const bf16x8*>(am + ks * 32);
#pragma unroll
      for (int ct = 0; ct < CT; ++ct)
        acc[rt][ct] = __builtin_amdgcn_mfma_f32_16x16x32_bf16(a, b[ct][ks], acc[rt][ct], 0, 0, 0);
    }
#pragma unroll
    for (int ks = 0; ks < 4; ++ks) {
      bf16x8 a = *reinterpret_cast<const bf16x8*>(ah + ks * 32);
#pragma unroll
      for (int ct = 0; ct < CT; ++ct)
        acc[rt][ct] = __builtin_amdgcn_mfma_f32_16x16x32_bf16(a, b[ct][ks + 4], acc[rt][ct], 0, 0, 0);
    }
  }

  // C/D layout: col = lane&15, row = (lane>>4)*4 + reg  [m89-verified]
#pragma unroll
  for (int rt = 0; rt < 4; ++rt) {
#pragma unroll
    for (int ct = 0; ct < CT; ++ct) {
      int col = c0 + ct * 16 + r16;
#pragma unroll
      for (int reg = 0; reg < 4; ++reg) {
        int row = r0 + rt * 16 + g * 4 + reg;
        if (row < N) {
          float v = acc[rt][ct][reg] + bias[ct];
          if (RELU) v = fmaxf(v, 0.0f);
          if (F32OUT)
            ((float*)outv)[(size_t)row * OC + col] = v;
          else
            ((ushort*)outv)[(size_t)row * OC + col] = f2bf(v);
        }
      }
    }
  }
}

extern "C" void kernel_launch(void* const* d_in, const int* in_sizes, int n_in,
                              void* d_out, int out_size, void* d_ws, size_t ws_size,
                              hipStream_t stream) {
  const float* x = (const float*)d_in[0];
  const int* ei = (const int*)d_in[1];
  const float* Wl0 = (const float*)d_in[2];
  const float* bl0 = (const float*)d_in[3];
  const float* Wr0 = (const float*)d_in[4];
  const float* Wl1 = (const float*)d_in[5];
  const float* bl1 = (const float*)d_in[6];
  const float* Wr1 = (const float*)d_in[7];
  const float* Wl2 = (const float*)d_in[8];
  const float* bl2 = (const float*)d_in[9];
  const float* Wr2 = (const float*)d_in[10];
  float* out = (float*)d_out;

  const int N = in_sizes[0] / D;  // 100000
  const int E = in_sizes[1] / 6;  // 625000

  char* ws = (char*)d_ws;
  size_t featB = (size_t)N * D * sizeof(ushort);  // 25.6 MB
  ushort* hb0 = (ushort*)ws;
  ushort* hb1 = (ushort*)(ws + featB);
  ushort* mb = (ushort*)(ws + 2 * featB);
  ushort* Wc0 = (ushort*)(ws + 3 * featB);
  ushort* Wc1 = Wc0 + 128 * 256;
  ushort* Wc2 = Wc1 + 128 * 256;
  int* cnt = (int*)(Wc2 + 64 * 256);  // [3N]
  int* row_start = cnt + 3 * N;       // [3N]
  int* cursor = row_start + 3 * N;    // [3N]
  int* bsums = cursor + 3 * N;        // [3*NB_SCAN]
  int* esrc = bsums + 3 * NB_SCAN;    // [3E]

  const int nbN = (N + 255) / 256;
  const int nbE = (E + 255) / 256;
  const int aggGrid = (N * 64 + 255) / 256;  // one wave per node, 4 waves/block
  const int linGrid = (N + 63) / 64;

  cvt_f32_bf16<<<2048, 256, 0, stream>>>((const float4*)x, (uint2*)hb0, (long)N * D / 4);
  prep_w<<<(128 * 256 + 255) / 256, 256, 0, stream>>>(Wl0, Wr0, Wc0, 128);
  prep_w<<<(128 * 256 + 255) / 256, 256, 0, stream>>>(Wl1, Wr1, Wc1, 128);
  prep_w<<<(64 * 256 + 255) / 256, 256, 0, stream>>>(Wl2, Wr2, Wc2, 64);

  // CSR build for all 3 layers, batched
  fill_int_zero<<<(3 * N + 255) / 256, 256, 0, stream>>>(cnt, 3 * N);
  count_dst_all<<<dim3(nbE, 3), 256, 0, stream>>>(ei, cnt, N, E);
  scan_block_all<<<dim3(nbN, 3), 256, 0, stream>>>(cnt, row_start, bsums, N);
  scan_sums_all<<<dim3(1, 3), NB_SCAN, 0, stream>>>(bsums, nbN);
  scan_fin_all<<<dim3(nbN, 3), 256, 0, stream>>>(row_start, bsums, cursor, N);
  fill_edges_all<<<dim3(nbE, 3), 256, 0, stream>>>(ei, cursor, esrc, N, E);

  for (int layer = 0; layer < 3; ++layer) {
    const ushort* hin = (layer == 1) ? hb1 : hb0;
    aggregate_mean<<<aggGrid, 256, 0, stream>>>(hin, esrc + (size_t)layer * E,
                                                row_start + (size_t)layer * N,
                                                cnt + (size_t)layer * N, mb, N);
    if (layer == 0)
      sage_linear_mfma<128, true, false><<<linGrid, 256, 0, stream>>>(mb, hb0, Wc0, bl0, hb1, N);
    else if (layer == 1)
      sage_linear_mfma<128, true, false><<<linGrid, 256, 0, stream>>>(mb, hb1, Wc1, bl1, hb0, N);
    else
      sage_linear_mfma<64, false, true><<<linGrid, 256, 0, stream>>>(mb, hb0, Wc2, bl2, out, N);
  }
}

// Round 6
// 482.063 us; speedup vs baseline: 1.2851x; 1.1895x over previous
//
#include <hip/hip_runtime.h>
#include <hip/hip_bf16.h>

constexpr int D = 128;
constexpr int NB_SCAN = 512;  // max scan blocks per layer (ceil(100000/256)=391)

using bf16x8 = __attribute__((ext_vector_type(8))) short;
using f32x4 = __attribute__((ext_vector_type(4))) float;

__device__ inline ushort f2bf(float f) {
  union { float f; uint u; } v; v.f = f;
  uint r = v.u + 0x7fff + ((v.u >> 16) & 1);
  return (ushort)(r >> 16);
}
__device__ inline float bflo(uint p) {
  union { uint u; float f; } v; v.u = p << 16; return v.f;
}
__device__ inline float bfhi(uint p) {
  union { uint u; float f; } v; v.u = p & 0xffff0000u; return v.f;
}

__global__ void fill_int_zero(int* __restrict__ p, int n) {
  int i = blockIdx.x * blockDim.x + threadIdx.x;
  if (i < n) p[i] = 0;
}

__global__ void cvt_f32_bf16(const float4* __restrict__ x, uint2* __restrict__ o, long n4) {
  long i = (long)blockIdx.x * blockDim.x + threadIdx.x;
  long stride = (long)gridDim.x * blockDim.x;
  for (; i < n4; i += stride) {
    float4 v = x[i];
    uint2 r;
    r.x = (uint)f2bf(v.x) | ((uint)f2bf(v.y) << 16);
    r.y = (uint)f2bf(v.z) | ((uint)f2bf(v.w) << 16);
    o[i] = r;
  }
}

// Combined weight, bf16, row-major [OC][256]: k<128 -> Wl[c][k], else Wr[c][k-128]
__global__ void prep_w(const float* __restrict__ Wl, const float* __restrict__ Wr,
                       ushort* __restrict__ Wc, int OC) {
  int t = blockIdx.x * blockDim.x + threadIdx.x;
  if (t < OC * 256) {
    int c = t >> 8, k = t & 255;
    float v = (k < 128) ? Wl[c * 128 + k] : Wr[c * 128 + (k - 128)];
    Wc[t] = f2bf(v);
  }
}

// ---- batched (3-layer) CSR build: blockIdx.y = layer ----
__global__ void count_dst_all(const int* __restrict__ ei, int* __restrict__ cnt, int N, int E) {
  int l = blockIdx.y;
  const int* dst = ei + (size_t)(2 * l + 1) * E;
  int e = blockIdx.x * 256 + threadIdx.x;
  if (e < E) atomicAdd(&cnt[l * N + dst[e]], 1);
}

__global__ void scan_block_all(const int* __restrict__ cnt, int* __restrict__ row_excl,
                               int* __restrict__ bsums, int N) {
  int l = blockIdx.y;
  __shared__ int sm[256];
  int i = blockIdx.x * 256 + threadIdx.x;
  int v = (i < N) ? cnt[l * N + i] : 0;
  sm[threadIdx.x] = v;
  __syncthreads();
  for (int off = 1; off < 256; off <<= 1) {
    int t = (threadIdx.x >= off) ? sm[threadIdx.x - off] : 0;
    __syncthreads();
    sm[threadIdx.x] += t;
    __syncthreads();
  }
  if (i < N) row_excl[l * N + i] = sm[threadIdx.x] - v;
  if (threadIdx.x == 255) bsums[l * NB_SCAN + blockIdx.x] = sm[255];
}

__global__ void scan_sums_all(int* __restrict__ bsums, int nb) {
  int l = blockIdx.y;
  __shared__ int sm[NB_SCAN];
  int v = (threadIdx.x < nb) ? bsums[l * NB_SCAN + threadIdx.x] : 0;
  sm[threadIdx.x] = v;
  __syncthreads();
  for (int off = 1; off < NB_SCAN; off <<= 1) {
    int t = (threadIdx.x >= off) ? sm[threadIdx.x - off] : 0;
    __syncthreads();
    sm[threadIdx.x] += t;
    __syncthreads();
  }
  if (threadIdx.x < nb) bsums[l * NB_SCAN + threadIdx.x] = sm[threadIdx.x] - v;
}

__global__ void scan_fin_all(int* __restrict__ row_start, const int* __restrict__ bsums,
                             int* __restrict__ cursor, int N) {
  int l = blockIdx.y;
  int i = blockIdx.x * 256 + threadIdx.x;
  if (i < N) {
    int v = row_start[l * N + i] + bsums[l * NB_SCAN + blockIdx.x];
    row_start[l * N + i] = v;
    cursor[l * N + i] = v;
  }
}

// XCD-range-partitioned edge fill. Round-5 counters showed 16x write amplification
// (117 MB HBM-side writes for 7.5 MB useful): each 64B esrc line's 16 slots were
// written by workgroups on all 8 XCDs -> 8 partial-line writebacks from 8 private L2s.
// Fix: dst-space split into 8 ranges; range r is handled only by blocks with
// blockIdx.x&7 == r, which the dispatcher round-robins onto XCD r [m09/m157].
// Each range's cursor+esrc window is then XCD-private -> lines fill completely in
// one L2 and write back once. dst[] is re-read 8x (LLC-resident, cheap).
constexpr int NRANGE = 8;
constexpr int CHUNK = 2048;  // edges per block
__global__ void fill_edges_xcd(const int* __restrict__ ei, int* __restrict__ cursor,
                               int* __restrict__ esrc, int N, int E) {
  int l = blockIdx.y;
  const int* src = ei + (size_t)(2 * l) * E;
  const int* dst = src + E;
  int r = blockIdx.x & (NRANGE - 1);
  int c = blockIdx.x >> 3;
  int rangeSz = (N + NRANGE - 1) / NRANGE;
  int lo = r * rangeSz;
  int hi = min(N, lo + rangeSz);
  int base = c * CHUNK;
  int end = min(base + CHUNK, E);
  for (int e = base + threadIdx.x; e < end; e += 256) {
    int d = dst[e];
    if (d >= lo && d < hi) {
      int pos = atomicAdd(&cursor[l * N + d], 1);
      esrc[(size_t)l * E + pos] = src[e];
    }
  }
}

// One 64-lane wave per node: gather-sum bf16 neighbor rows (fp32 acc), write bf16 mean.
// 8-wide predicated unroll: avg degree is 6.25, so typically ONE latency round.
__global__ void aggregate_mean(const ushort* __restrict__ h, const int* __restrict__ esrc,
                               const int* __restrict__ row_start, const int* __restrict__ cnt,
                               ushort* __restrict__ mean, int N) {
  int node = blockIdx.x * (blockDim.x >> 6) + (threadIdx.x >> 6);
  if (node >= N) return;
  int lane = threadIdx.x & 63;
  int start = row_start[node];
  int deg = cnt[node];
  const uint* hp = (const uint*)h;  // row stride 64 uints
  float ax[8], ay[8];
#pragma unroll
  for (int u = 0; u < 8; ++u) { ax[u] = 0.f; ay[u] = 0.f; }
  for (int j = 0; j < deg; j += 8) {
    int idx[8];
#pragma unroll
    for (int u = 0; u < 8; ++u) idx[u] = (j + u < deg) ? esrc[start + j + u] : -1;
#pragma unroll
    for (int u = 0; u < 8; ++u) {
      if (idx[u] >= 0) {
        uint v = hp[(size_t)idx[u] * 64 + lane];
        ax[u] += bflo(v);
        ay[u] += bfhi(v);
      }
    }
  }
  float sx = ((ax[0] + ax[1]) + (ax[2] + ax[3])) + ((ax[4] + ax[5]) + (ax[6] + ax[7]));
  float sy = ((ay[0] + ay[1]) + (ay[2] + ay[3])) + ((ay[4] + ay[5]) + (ay[6] + ay[7]));
  float inv = 1.0f / fmaxf((float)deg, 1.0f);
  uint r = (uint)f2bf(sx * inv) | ((uint)f2bf(sy * inv) << 16);
  ((uint*)mean)[(size_t)node * 64 + lane] = r;
}

// MFMA linear: C[N x OC] = [mean|h] (N x 256, bf16) @ Wc^T + bl, optional relu.
// Block: 64 rows x OC cols, 4 waves; wave w owns cols [w*OC/4, +OC/4) (CT 16-col tiles),
// B-frags held in registers (Wc row-major => contiguous 16B frag loads).
template <int OC, bool RELU, bool F32OUT>
__global__ void sage_linear_mfma(const ushort* __restrict__ mb, const ushort* __restrict__ hb,
                                 const ushort* __restrict__ Wc, const float* __restrict__ bl,
                                 void* __restrict__ outv, int N) {
  constexpr int CT = OC / 64;  // col-tiles per wave: 128 -> 2, 64 -> 1
  int tid = threadIdx.x;
  int w = tid >> 6, lane = tid & 63;
  int g = lane >> 4, r16 = lane & 15;
  int r0 = blockIdx.x * 64;
  int c0 = w * (OC / 4);

  bf16x8 b[CT][8];
  float bias[CT];
#pragma unroll
  for (int ct = 0; ct < CT; ++ct) {
    int col = c0 + ct * 16 + r16;
    const ushort* wrow = Wc + (size_t)col * 256 + g * 8;
#pragma unroll
    for (int ks = 0; ks < 8; ++ks)
      b[ct][ks] = *reinterpret_cast<const bf16x8*>(wrow + ks * 32);
    bias[ct] = bl[col];
  }

  f32x4 acc[4][CT];
#pragma unroll
  for (int rt = 0; rt < 4; ++rt)
#pragma unroll
    for (int ct = 0; ct < CT; ++ct)
      acc[rt][ct] = (f32x4){0.f, 0.f, 0.f, 0.f};

#pragma unroll
  for (int rt = 0; rt < 4; ++rt) {
    int row = r0 + rt * 16 + r16;
    row = min(row, N - 1);
    const ushort* am = mb + (size_t)row * 128 + g * 8;
    const ushort* ah = hb + (size_t)row * 128 + g * 8;
#pragma unroll
    for (int ks = 0; ks < 4; ++ks) {
      bf16x8 a = *reinterpret_cast<const bf16x8*>(am + ks * 32);
#pragma unroll
      for (int ct = 0; ct < CT; ++ct)
        acc[rt][ct] = __builtin_amdgcn_mfma_f32_16x16x32_bf16(a, b[ct][ks], acc[rt][ct], 0, 0, 0);
    }
#pragma unroll
    for (int ks = 0; ks < 4; ++ks) {
      bf16x8 a = *reinterpret_cast<const bf16x8*>(ah + ks * 32);
#pragma unroll
      for (int ct = 0; ct < CT; ++ct)
        acc[rt][ct] = __builtin_amdgcn_mfma_f32_16x16x32_bf16(a, b[ct][ks + 4], acc[rt][ct], 0, 0, 0);
    }
  }

  // C/D layout: col = lane&15, row = (lane>>4)*4 + reg  [m89-verified]
#pragma unroll
  for (int rt = 0; rt < 4; ++rt) {
#pragma unroll
    for (int ct = 0; ct < CT; ++ct) {
      int col = c0 + ct * 16 + r16;
#pragma unroll
      for (int reg = 0; reg < 4; ++reg) {
        int row = r0 + rt * 16 + g * 4 + reg;
        if (row < N) {
          float v = acc[rt][ct][reg] + bias[ct];
          if (RELU) v = fmaxf(v, 0.0f);
          if (F32OUT)
            ((float*)outv)[(size_t)row * OC + col] = v;
          else
            ((ushort*)outv)[(size_t)row * OC + col] = f2bf(v);
        }
      }
    }
  }
}

extern "C" void kernel_launch(void* const* d_in, const int* in_sizes, int n_in,
                              void* d_out, int out_size, void* d_ws, size_t ws_size,
                              hipStream_t stream) {
  const float* x = (const float*)d_in[0];
  const int* ei = (const int*)d_in[1];
  const float* Wl0 = (const float*)d_in[2];
  const float* bl0 = (const float*)d_in[3];
  const float* Wr0 = (const float*)d_in[4];
  const float* Wl1 = (const float*)d_in[5];
  const float* bl1 = (const float*)d_in[6];
  const float* Wr1 = (const float*)d_in[7];
  const float* Wl2 = (const float*)d_in[8];
  const float* bl2 = (const float*)d_in[9];
  const float* Wr2 = (const float*)d_in[10];
  float* out = (float*)d_out;

  const int N = in_sizes[0] / D;  // 100000
  const int E = in_sizes[1] / 6;  // 625000

  char* ws = (char*)d_ws;
  size_t featB = (size_t)N * D * sizeof(ushort);  // 25.6 MB
  ushort* hb0 = (ushort*)ws;
  ushort* hb1 = (ushort*)(ws + featB);
  ushort* mb = (ushort*)(ws + 2 * featB);
  ushort* Wc0 = (ushort*)(ws + 3 * featB);
  ushort* Wc1 = Wc0 + 128 * 256;
  ushort* Wc2 = Wc1 + 128 * 256;
  int* cnt = (int*)(Wc2 + 64 * 256);  // [3N]
  int* row_start = cnt + 3 * N;       // [3N]
  int* cursor = row_start + 3 * N;    // [3N]
  int* bsums = cursor + 3 * N;        // [3*NB_SCAN]
  int* esrc = bsums + 3 * NB_SCAN;    // [3E]

  const int nbN = (N + 255) / 256;
  const int nbE = (E + 255) / 256;
  const int aggGrid = (N * 64 + 255) / 256;  // one wave per node, 4 waves/block
  const int linGrid = (N + 63) / 64;
  const int fillChunks = (E + CHUNK - 1) / CHUNK;

  cvt_f32_bf16<<<2048, 256, 0, stream>>>((const float4*)x, (uint2*)hb0, (long)N * D / 4);
  prep_w<<<(128 * 256 + 255) / 256, 256, 0, stream>>>(Wl0, Wr0, Wc0, 128);
  prep_w<<<(128 * 256 + 255) / 256, 256, 0, stream>>>(Wl1, Wr1, Wc1, 128);
  prep_w<<<(64 * 256 + 255) / 256, 256, 0, stream>>>(Wl2, Wr2, Wc2, 64);

  // CSR build for all 3 layers, batched
  fill_int_zero<<<(3 * N + 255) / 256, 256, 0, stream>>>(cnt, 3 * N);
  count_dst_all<<<dim3(nbE, 3), 256, 0, stream>>>(ei, cnt, N, E);
  scan_block_all<<<dim3(nbN, 3), 256, 0, stream>>>(cnt, row_start, bsums, N);
  scan_sums_all<<<dim3(1, 3), NB_SCAN, 0, stream>>>(bsums, nbN);
  scan_fin_all<<<dim3(nbN, 3), 256, 0, stream>>>(row_start, bsums, cursor, N);
  fill_edges_xcd<<<dim3(fillChunks * NRANGE, 3), 256, 0, stream>>>(ei, cursor, esrc, N, E);

  for (int layer = 0; layer < 3; ++layer) {
    const ushort* hin = (layer == 1) ? hb1 : hb0;
    aggregate_mean<<<aggGrid, 256, 0, stream>>>(hin, esrc + (size_t)layer * E,
                                                row_start + (size_t)layer * N,
                                                cnt + (size_t)layer * N, mb, N);
    if (layer == 0)
      sage_linear_mfma<128, true, false><<<linGrid, 256, 0, stream>>>(mb, hb0, Wc0, bl0, hb1, N);
    else if (layer == 1)
      sage_linear_mfma<128, true, false><<<linGrid, 256, 0, stream>>>(mb, hb1, Wc1, bl1, hb0, N);
    else
      sage_linear_mfma<64, false, true><<<linGrid, 256, 0, stream>>>(mb, hb0, Wc2, bl2, out, N);
  }
}